// Round 2
// baseline (626.514 us; speedup 1.0000x reference)
//
#include <hip/hip_runtime.h>
#include <hip/hip_bf16.h>
#include <cstdint>
#include <cstddef>

// AttentionModule N=65536, C=D=512, L=16.
// Math (L-expand makes softmax uniform; attention branch cancels):
//   pos  = relu(features @ Wk^T)
//   pv   = sigmoid(pos @ Wvc^T) * pos
//   hmid = relu(bn1(features2 @ Wv1^T))
//   out  = relu(bn2(hmid @ Wv2^T)) + pv
//
// Fused into TWO kernels, one 64-row panel per block:
//   fusedA: f -> LDS, GEMM1(relu)->LDS, GEMM2 -> pv (packed bf16 ws)
//   fusedB: f2 -> LDS, GEMM3(relu.bn1)->LDS, GEMM4(relu.bn2)+pv -> out
// B fragments are read straight from global (weights are L2-resident bf16),
// prefetched 2 K-steps deep -> no barriers inside the K-loop.
// pv is stored in per-thread fragment order (coalesced 8B/lane) since both
// kernels use the identical block/wave -> tile mapping.

#define DIM 512
#define NROWS 65536
#define MBLK 64

typedef __bf16 bf16;
typedef __attribute__((ext_vector_type(8))) __bf16 bf16x8;
typedef __attribute__((ext_vector_type(4))) __bf16 bf16x4;
typedef __attribute__((ext_vector_type(4))) float f32x4;

__device__ __forceinline__ float sigmoidf_(float x) {
  return 1.0f / (1.0f + __expf(-x));
}

// Swizzled LDS byte offset into a [64][512] bf16 panel (row stride 1024 B).
// XOR of (row&15)<<4 spreads an MFMA A-fragment's 16 rows across 16 distinct
// 16B slots -> max 2-way bank aliasing on ds_read_b128 (free, m136).
__device__ __forceinline__ int lds_off(int row, int cb) {
  return row * (DIM * 2) + (cb ^ ((row & 15) << 4));
}

// fp32 -> bf16 elementwise, vectorized x4. n4 = n/4.
__global__ __launch_bounds__(256) void cvt_f32_bf16(
    const float* __restrict__ s, bf16* __restrict__ d, int n4) {
  int i = blockIdx.x * 256 + threadIdx.x;
  if (i < n4) {
    f32x4 v = ((const f32x4*)s)[i];
    bf16x4 o;
    o[0] = (bf16)v[0]; o[1] = (bf16)v[1]; o[2] = (bf16)v[2]; o[3] = (bf16)v[3];
    ((bf16x4*)d)[i] = o;
  }
}

// Stage a 64x512 fp32 panel -> bf16, swizzled, into LDS. 512 threads.
// Lane-contiguous 32B global reads; 16B LDS writes, swizzle preserves
// 16B-chunk granularity (bits 0-3 untouched).
__device__ __forceinline__ void stage_panel(char* As, const float* __restrict__ g,
                                            int t) {
#pragma unroll
  for (int it = 0; it < 8; ++it) {
    int c = it * 512 + t;  // 16B-chunk id, 0..4095
    f32x4 v0 = *(const f32x4*)(g + (size_t)c * 8);
    f32x4 v1 = *(const f32x4*)(g + (size_t)c * 8 + 4);
    bf16x8 o;
    o[0] = (bf16)v0[0]; o[1] = (bf16)v0[1]; o[2] = (bf16)v0[2]; o[3] = (bf16)v0[3];
    o[4] = (bf16)v1[0]; o[5] = (bf16)v1[1]; o[6] = (bf16)v1[2]; o[7] = (bf16)v1[3];
    *(bf16x8*)(As + lds_off(c >> 6, (c & 63) * 16)) = o;
  }
}

// Per-wave 64(M)x64(N) tile: acc += As(64x512 bf16, swizzled LDS) @ W[wn:wn+64,:]^T.
// B fragments straight from global (L2-resident), double-prefetched 2 K-steps.
__device__ __forceinline__ void gemm_core(f32x4 (&acc)[4][4], const char* As,
                                          const bf16* __restrict__ W, int lr,
                                          int kq, int wn) {
  const bf16* bp = W + (size_t)(wn + lr) * DIM + kq * 8;
  bf16x8 bq0[4], bq1[4], bq2[4];
#pragma unroll
  for (int j = 0; j < 4; j++) bq0[j] = *(const bf16x8*)(bp + j * 16 * DIM);
#pragma unroll
  for (int j = 0; j < 4; j++) bq1[j] = *(const bf16x8*)(bp + j * 16 * DIM + 32);
#pragma unroll
  for (int j = 0; j < 4; j++) bq2[j] = bq1[j];  // defined value; dead on tail
  for (int kb = 0; kb < DIM; kb += 32) {
    bf16x8 a[4];
#pragma unroll
    for (int i = 0; i < 4; i++)
      a[i] = *(const bf16x8*)(As + (i * 16 + lr) * (DIM * 2) +
                              ((kb * 2 + kq * 16) ^ (lr << 4)));
    if (kb + 64 < DIM) {
#pragma unroll
      for (int j = 0; j < 4; j++)
        bq2[j] = *(const bf16x8*)(bp + j * 16 * DIM + kb + 64);
    }
#pragma unroll
    for (int i = 0; i < 4; i++)
#pragma unroll
      for (int j = 0; j < 4; j++)
        acc[i][j] = __builtin_amdgcn_mfma_f32_16x16x32_bf16(a[i], bq0[j],
                                                            acc[i][j], 0, 0, 0);
#pragma unroll
    for (int j = 0; j < 4; j++) {
      bq0[j] = bq1[j];
      bq1[j] = bq2[j];
    }
  }
}

// Kernel A: pos = relu(f @ Wk^T); pv = sigmoid(pos @ Wvc^T) * pos -> packed ws.
__global__ __launch_bounds__(512, 2) void fusedA(
    const float* __restrict__ f, const bf16* __restrict__ Wk,
    const bf16* __restrict__ Wvc, bf16x4* __restrict__ pvws) {
  __shared__ __align__(16) char As[MBLK * DIM * 2];
  const int t = threadIdx.x;
  const int lane = t & 63;
  const int lr = lane & 15;
  const int kq = lane >> 4;
  const int wn = (t >> 6) * 64;
  const size_t m0 = (size_t)blockIdx.x * MBLK;

  stage_panel(As, f + m0 * DIM, t);
  __syncthreads();

  f32x4 acc[4][4];
#pragma unroll
  for (int i = 0; i < 4; i++)
#pragma unroll
    for (int j = 0; j < 4; j++) acc[i][j] = (f32x4){0.f, 0.f, 0.f, 0.f};
  gemm_core(acc, As, Wk, lr, kq, wn);

  __syncthreads();  // all waves done reading f-panel; overwrite with pos
#pragma unroll
  for (int i = 0; i < 4; i++)
#pragma unroll
    for (int j = 0; j < 4; j++)
#pragma unroll
      for (int r = 0; r < 4; r++) {
        int m = i * 16 + kq * 4 + r;
        int n = wn + j * 16 + lr;
        *(bf16*)(As + lds_off(m, n * 2)) = (bf16)fmaxf(acc[i][j][r], 0.f);
      }
  __syncthreads();

#pragma unroll
  for (int i = 0; i < 4; i++)
#pragma unroll
    for (int j = 0; j < 4; j++) acc[i][j] = (f32x4){0.f, 0.f, 0.f, 0.f};
  gemm_core(acc, As, Wvc, lr, kq, wn);

#pragma unroll
  for (int i = 0; i < 4; i++)
#pragma unroll
    for (int j = 0; j < 4; j++) {
      bf16x4 o;
#pragma unroll
      for (int r = 0; r < 4; r++) {
        int m = i * 16 + kq * 4 + r;
        int n = wn + j * 16 + lr;
        float p = (float)(*(const bf16*)(As + lds_off(m, n * 2)));
        o[r] = (bf16)(sigmoidf_(acc[i][j][r]) * p);
      }
      // packed per-thread fragment order, lane-contiguous (coalesced 8B/lane)
      pvws[((size_t)blockIdx.x * 16 + i * 4 + j) * 512 + t] = o;
    }
}

// Kernel B: hmid = relu(bn1(f2 @ Wv1^T)); out = relu(bn2(hmid @ Wv2^T)) + pv.
__global__ __launch_bounds__(512, 2) void fusedB(
    const float* __restrict__ f2, const bf16* __restrict__ Wv1,
    const bf16* __restrict__ Wv2, const bf16x4* __restrict__ pvws,
    float* __restrict__ out, const float* __restrict__ bg1,
    const float* __restrict__ bb1, const float* __restrict__ bm1,
    const float* __restrict__ bv1, const float* __restrict__ bg2,
    const float* __restrict__ bb2, const float* __restrict__ bm2,
    const float* __restrict__ bv2) {
  __shared__ __align__(16) char As[MBLK * DIM * 2];
  const int t = threadIdx.x;
  const int lane = t & 63;
  const int lr = lane & 15;
  const int kq = lane >> 4;
  const int wn = (t >> 6) * 64;
  const size_t m0 = (size_t)blockIdx.x * MBLK;

  stage_panel(As, f2 + m0 * DIM, t);
  __syncthreads();

  f32x4 acc[4][4];
#pragma unroll
  for (int i = 0; i < 4; i++)
#pragma unroll
    for (int j = 0; j < 4; j++) acc[i][j] = (f32x4){0.f, 0.f, 0.f, 0.f};
  gemm_core(acc, As, Wv1, lr, kq, wn);

  float iv1[4], bc1[4];
#pragma unroll
  for (int j = 0; j < 4; j++) {
    int c = wn + j * 16 + lr;
    float s = bg1[c] * rsqrtf(bv1[c] + 1e-5f);
    iv1[j] = s;
    bc1[j] = bb1[c] - bm1[c] * s;
  }

  __syncthreads();  // all waves done reading f2-panel; overwrite with hmid
#pragma unroll
  for (int i = 0; i < 4; i++)
#pragma unroll
    for (int j = 0; j < 4; j++)
#pragma unroll
      for (int r = 0; r < 4; r++) {
        int m = i * 16 + kq * 4 + r;
        int n = wn + j * 16 + lr;
        float v = fmaxf(acc[i][j][r] * iv1[j] + bc1[j], 0.f);
        *(bf16*)(As + lds_off(m, n * 2)) = (bf16)v;
      }
  __syncthreads();

#pragma unroll
  for (int i = 0; i < 4; i++)
#pragma unroll
    for (int j = 0; j < 4; j++) acc[i][j] = (f32x4){0.f, 0.f, 0.f, 0.f};
  gemm_core(acc, As, Wv2, lr, kq, wn);

  float iv2[4], bc2[4];
#pragma unroll
  for (int j = 0; j < 4; j++) {
    int c = wn + j * 16 + lr;
    float s = bg2[c] * rsqrtf(bv2[c] + 1e-5f);
    iv2[j] = s;
    bc2[j] = bb2[c] - bm2[c] * s;
  }

#pragma unroll
  for (int i = 0; i < 4; i++)
#pragma unroll
    for (int j = 0; j < 4; j++) {
      bf16x4 pv = pvws[((size_t)blockIdx.x * 16 + i * 4 + j) * 512 + t];
#pragma unroll
      for (int r = 0; r < 4; r++) {
        int m = i * 16 + kq * 4 + r;
        int n = wn + j * 16 + lr;
        float v = fmaxf(acc[i][j][r] * iv2[j] + bc2[j], 0.f) + (float)pv[r];
        out[(m0 + m) * DIM + n] = v;
      }
    }
}

extern "C" void kernel_launch(void* const* d_in, const int* in_sizes, int n_in,
                              void* d_out, int out_size, void* d_ws,
                              size_t ws_size, hipStream_t stream) {
  const float* features  = (const float*)d_in[0];
  const float* features2 = (const float*)d_in[1];
  const float* Wk  = (const float*)d_in[2];
  const float* Wv1 = (const float*)d_in[3];
  const float* Wv2 = (const float*)d_in[4];
  const float* g1 = (const float*)d_in[5];
  const float* b1 = (const float*)d_in[6];
  const float* m1 = (const float*)d_in[7];
  const float* v1 = (const float*)d_in[8];
  const float* g2 = (const float*)d_in[9];
  const float* b2 = (const float*)d_in[10];
  const float* m2 = (const float*)d_in[11];
  const float* v2 = (const float*)d_in[12];
  // d_in[13] Wa, d_in[14] Wqk: cancelled, unused.
  const float* Wvc = (const float*)d_in[15];
  float* out = (float*)d_out;

  // ws (bf16): wk | wv1 | wv2 | wvc | pv(packed)  ~= 66 MiB total.
  bf16* wkb  = (bf16*)d_ws;
  bf16* wv1b = wkb + (size_t)DIM * DIM;
  bf16* wv2b = wv1b + (size_t)DIM * DIM;
  bf16* wvcb = wv2b + (size_t)DIM * DIM;
  bf16* pvws = wvcb + (size_t)DIM * DIM;

  {
    int n4 = DIM * DIM / 4;  // 65536
    dim3 cg(n4 / 256), cb(256);
    cvt_f32_bf16<<<cg, cb, 0, stream>>>(Wk, wkb, n4);
    cvt_f32_bf16<<<cg, cb, 0, stream>>>(Wvc, wvcb, n4);
    cvt_f32_bf16<<<cg, cb, 0, stream>>>(Wv1, wv1b, n4);
    cvt_f32_bf16<<<cg, cb, 0, stream>>>(Wv2, wv2b, n4);
  }

  dim3 grid(NROWS / MBLK);  // 1024 blocks, 512 threads (8 waves)
  dim3 block(512);
  fusedA<<<grid, block, 0, stream>>>(features, wkb, wvcb, (bf16x4*)pvws);
  fusedB<<<grid, block, 0, stream>>>(features2, wv1b, wv2b,
                                     (const bf16x4*)pvws, out,
                                     g1, b1, m1, v1, g2, b2, m2, v2);
}